// Round 1
// baseline (588.604 us; speedup 1.0000x reference)
//
#include <hip/hip_runtime.h>
#include <hip/hip_bf16.h>
#include <stdint.h>

typedef __bf16 bf16x8 __attribute__((ext_vector_type(8)));
typedef float f32x4 __attribute__((ext_vector_type(4)));
typedef unsigned short u16;
typedef u16 u16x8 __attribute__((ext_vector_type(8)));
typedef u16 u16x4 __attribute__((ext_vector_type(4)));

// Problem constants: B=16, C=32, H=W=128, K=8 -> P=256, M=K=8192, N=1024.
#define MD 8192
#define KD 8192
#define ND 1024

__device__ __forceinline__ u16 f32_to_bf16(float f) {
  uint32_t u = __float_as_uint(f);
  u += 0x7FFFu + ((u >> 16) & 1u);   // round-to-nearest-even
  return (u16)(u >> 16);
}

__device__ __forceinline__ void load_lds16(const void* g, void* l) {
  __builtin_amdgcn_global_load_lds(
      (const __attribute__((address_space(1))) void*)g,
      (__attribute__((address_space(3))) void*)l, 16, 0, 0);
}

// ---- kernel 1: g (8192x8192 fp32) -> bf16, 4 float4/thread grid ----
__global__ __launch_bounds__(256) void convert_g(const float* __restrict__ g,
                                                 u16* __restrict__ gb) {
  const size_t base = (size_t)blockIdx.x * 1024 + threadIdx.x;
#pragma unroll
  for (int q = 0; q < 4; ++q) {
    const size_t t = base + (size_t)q * 256;      // coalesced per iteration
    float4 a = ((const float4*)g)[t];
    u16x4 r;
    r[0] = f32_to_bf16(a.x); r[1] = f32_to_bf16(a.y);
    r[2] = f32_to_bf16(a.z); r[3] = f32_to_bf16(a.w);
    ((u16x4*)gb)[t] = r;
  }
}

// ---- kernel 2: build B^T via full-plane LDS transpose ----
// One block per (n, ci) plane (512 blocks). Reads 128x128 fp32 coalesced,
// writes bt rows as 512B-contiguous segments (was: 16B scatter at 16KB stride).
// bt[n*64 + kk*8 + j][ci*256 + hy*16 + wx] = x[n][ci][hy*8+kk][wx*8+j]
#define LSTR 280   // u16 row stride: 560B, mult of 16 (aligned b128 reads),
                   // 140 words -> row-parity spreads banks (no 4x pattern)
__global__ __launch_bounds__(256) void build_b(const float* __restrict__ x,
                                               u16* __restrict__ bt) {
  __shared__ u16 L[64 * LSTR];                    // 35 KB, out-layout plane
  const int tid = threadIdx.x;
  const int n = blockIdx.x >> 5, ci = blockIdx.x & 31;
  const float* src = x + (size_t)blockIdx.x * 16384;
#pragma unroll
  for (int q = 0; q < 16; ++q) {
    const int p = q * 256 + tid;                  // float4 index in plane
    float4 v = ((const float4*)src)[p];           // coalesced 1KB/wave-instr
    const int h = p >> 5;                         // 0..127
    const int w4 = (p & 31) << 2;                 // w of .x ; w4..w4+3 same wx
    const int er0 = ((h & 7) << 3) + (w4 & 7);    // kk*8 + j0 (j0 in {0,4})
    const int ec = ((h >> 3) << 4) + (w4 >> 3);   // hy*16 + wx
    u16* Lp = L + ec;
    Lp[(er0 + 0) * LSTR] = f32_to_bf16(v.x);
    Lp[(er0 + 1) * LSTR] = f32_to_bf16(v.y);
    Lp[(er0 + 2) * LSTR] = f32_to_bf16(v.z);
    Lp[(er0 + 3) * LSTR] = f32_to_bf16(v.w);
  }
  __syncthreads();
  const int rr = tid >> 5;                        // 0..7
  const int c = tid & 31;                         // 0..31 (u16x8 chunks)
#pragma unroll
  for (int p = 0; p < 8; ++p) {
    const int r = (p << 3) + rr;                  // bt-row within plane 0..63
    u16x8 vv = *(const u16x8*)(L + r * LSTR + (c << 3));
    *(u16x8*)(bt + (size_t)((n << 6) + r) * KD + (ci << 8) + (c << 3)) = vv;
  }
}

// ---- kernel 3: C = A*B^T, 128x128 tiles (m97-structure: acc 4x4, BK=32, ----
// ---- width-16 global_load_lds), 512 blocks, XCD-pinned swizzle, fused  ----
// ---- permute+residual epilogue ----
__global__ __launch_bounds__(256) void gemm_bt(
    const u16* __restrict__ A,    // 8192 x 8192 bf16
    const u16* __restrict__ B,    // 1024 x 8192 bf16 (B^T)
    const float* __restrict__ X,  // residual
    float* __restrict__ out) {
  __shared__ u16 As[128 * 32];    // 8 KB
  __shared__ u16 Bs[128 * 32];    // 8 KB
  const int tid  = threadIdx.x;
  const int wave = tid >> 6;
  const int lane = tid & 63;

  // 64 M-tiles x 8 N-tiles; all 8 N-blocks of an M-tile have lin%8 == mb%8
  // -> one XCD, A-tile fetched once per XCD L2 (all 64 blocks/XCD co-resident)
  const int lin = blockIdx.x;          // 0..511
  const int mb = lin & 63;
  const int nb = lin >> 6;             // 0..7
  const int m0 = mb << 7;
  const int n0 = nb << 7;

  // staging: 256 threads x 16B = 4KB/instr = 64 rows x 32 k; 2 instrs each
  const int mst = tid >> 2;            // 0..63
  const int kst = (tid & 3) << 3;      // k elem 0,8,16,24
  const u16* gA0 = A + (size_t)(m0 + mst) * KD + kst;
  const u16* gA1 = gA0 + (size_t)64 * KD;
  const u16* gB0 = B + (size_t)(n0 + mst) * KD + kst;
  const u16* gB1 = gB0 + (size_t)64 * KD;
  char* ldsA = (char*)As + (wave << 10);   // wave-uniform base, lane*16 linear
  char* ldsB = (char*)Bs + (wave << 10);

  const int wm = wave & 1, wn = wave >> 1; // wave tile 64x64
  const int lm = lane & 15;
  const int kg = (lane >> 4) << 3;         // k elem 0,8,16,24
  const u16* fA = As + ((wm << 6) + lm) * 32 + kg;
  const u16* fB = Bs + ((wn << 6) + lm) * 32 + kg;

  f32x4 acc[4][4];
#pragma unroll
  for (int i = 0; i < 4; ++i)
#pragma unroll
    for (int j = 0; j < 4; ++j)
      acc[i][j] = (f32x4){0.f, 0.f, 0.f, 0.f};

  for (int kt = 0; kt < KD / 32; ++kt) {
    const int k0 = kt << 5;
    __syncthreads();
    load_lds16(gA0 + k0, ldsA);
    load_lds16(gA1 + k0, ldsA + 4096);
    load_lds16(gB0 + k0, ldsB);
    load_lds16(gB1 + k0, ldsB + 4096);
    __syncthreads();
    bf16x8 av[4], bv[4];
#pragma unroll
    for (int i = 0; i < 4; ++i) av[i] = *(const bf16x8*)(fA + i * 16 * 32);
#pragma unroll
    for (int j = 0; j < 4; ++j) bv[j] = *(const bf16x8*)(fB + j * 16 * 32);
#pragma unroll
    for (int i = 0; i < 4; ++i)
#pragma unroll
      for (int j = 0; j < 4; ++j)
        acc[i][j] = __builtin_amdgcn_mfma_f32_16x16x32_bf16(av[i], bv[j], acc[i][j], 0, 0, 0);
  }

  // epilogue: C/D layout col=lane&15, row=(lane>>4)*4+reg  [m89-verified]
  const int r4 = (lane >> 4) << 2;
#pragma unroll
  for (int i = 0; i < 4; ++i) {
    const int obase = m0 + (wm << 6) + (i << 4) + r4;
#pragma unroll
    for (int j = 0; j < 4; ++j) {
      const int cg = n0 + (wn << 6) + (j << 4) + lm;
      const int nn = cg >> 6, kk = (cg >> 3) & 7, jc = cg & 7;
#pragma unroll
      for (int reg = 0; reg < 4; ++reg) {
        const int oo = obase + reg;
        const int co = oo >> 8, hy = (oo >> 4) & 15, wx = oo & 15;
        const size_t idx =
            ((size_t)((nn << 5) + co) * 128 + (hy << 3) + kk) * 128 + (wx << 3) + jc;
        out[idx] = acc[i][j][reg] + X[idx];
      }
    }
  }
}

extern "C" void kernel_launch(void* const* d_in, const int* in_sizes, int n_in,
                              void* d_out, int out_size, void* d_ws, size_t ws_size,
                              hipStream_t stream) {
  const float* x = (const float*)d_in[0];       // (16,32,128,128) fp32
  const float* g = (const float*)d_in[1];       // (8192,8192) fp32
  float* out = (float*)d_out;                   // (16,32,128,128) fp32

  u16* gb = (u16*)d_ws;                         // 8192*8192 bf16 = 128 MiB
  u16* bt = gb + (size_t)MD * KD;               // 1024*8192 bf16 = 16 MiB

  convert_g<<<16384, 256, 0, stream>>>(g, gb);
  build_b<<<512, 256, 0, stream>>>(x, bt);
  gemm_bt<<<512, 256, 0, stream>>>(gb, bt, x, out);
}